// Round 6
// baseline (517.538 us; speedup 1.0000x reference)
//
#include <hip/hip_runtime.h>
#include <hip/hip_fp16.h>

#define IN_CH 11
#define HID 64
#define PAD 64
#define OVCAP 16384

typedef _Float16 half8_t __attribute__((ext_vector_type(8)));
typedef float f32x4_t __attribute__((ext_vector_type(4)));

// ---------------- setup kernels ----------------

__global__ void k_copyx(const float* __restrict__ x, float* __restrict__ xp, int N) {
    int i = blockIdx.x * blockDim.x + threadIdx.x;
    if (i < (N + 1) * 16) {
        int row = i >> 4, c = i & 15;
        xp[i] = (row < N && c < IN_CH) ? x[row * IN_CH + c] : 0.f;
    }
}

__global__ void k_fillpad(int4* __restrict__ col4, int n4, int N) {
    int i = blockIdx.x * blockDim.x + threadIdx.x;
    if (i < n4) col4[i] = make_int4(N, N, N, N);
}

// merged count+scatter: one atomic pass builds degree AND fills the padded rows
__global__ void k_build(const int* __restrict__ src, const int* __restrict__ dst,
                        int* __restrict__ cnt, int* __restrict__ col64,
                        int* __restrict__ ovcnt, int* __restrict__ ov, int E) {
    int e = blockIdx.x * blockDim.x + threadIdx.x;
    if (e < E) {
        int d = dst[e], s = src[e];
        int p = atomicAdd(&cnt[d], 1);
        if (p < PAD) {
            col64[d * PAD + p] = s;
        } else {
            int q = atomicAdd(ovcnt, 1);
            if (q < OVCAP) { ov[2 * q] = d; ov[2 * q + 1] = s; }
        }
    }
}

// fp32 weights (64x64) -> fp16, row-major
__global__ void k_cvtw(const float* __restrict__ Wl2, const float* __restrict__ Wr2,
                       __half* __restrict__ wl2h, __half* __restrict__ wr2h) {
    int i = blockIdx.x * blockDim.x + threadIdx.x;
    if (i < HID * HID) {
        wl2h[i] = __float2half_rn(Wl2[i]);
        wr2h[i] = __float2half_rn(Wr2[i]);
    }
}

// ---------------- layer 1 aggregate: sum of x rows (fp32) ----------------
__global__ void k_agg1(const float4* __restrict__ xp4, const int* __restrict__ col64,
                       float4* __restrict__ agg14, int N) {
    int lane = threadIdx.x & 63;
    int n = blockIdx.x * 4 + (threadIdx.x >> 6);
    if (n >= N) return;
    int c4 = lane & 3, sub = lane >> 2;
    const int* cb = col64 + n * PAD;
    int s[4];
    #pragma unroll
    for (int jj = 0; jj < 4; jj++) s[jj] = cb[sub + 16 * jj];
    float4 v[4];
    #pragma unroll
    for (int jj = 0; jj < 4; jj++) v[jj] = xp4[s[jj] * 4 + c4];
    float4 a;
    a.x = (v[0].x + v[1].x) + (v[2].x + v[3].x);
    a.y = (v[0].y + v[1].y) + (v[2].y + v[3].y);
    a.z = (v[0].z + v[1].z) + (v[2].z + v[3].z);
    a.w = (v[0].w + v[1].w) + (v[2].w + v[3].w);
    #pragma unroll
    for (int off = 4; off <= 32; off <<= 1) {
        a.x += __shfl_xor(a.x, off); a.y += __shfl_xor(a.y, off);
        a.z += __shfl_xor(a.z, off); a.w += __shfl_xor(a.w, off);
    }
    if (lane < 4) agg14[n * 4 + lane] = a;
}

__global__ void k_ov1(const int* __restrict__ ovcnt, const int* __restrict__ ov,
                      const float* __restrict__ x, float* __restrict__ agg1) {
    int c = *ovcnt; if (c > OVCAP) c = OVCAP;
    for (int i = blockIdx.x * blockDim.x + threadIdx.x; i < c;
         i += gridDim.x * blockDim.x) {
        int d = ov[2 * i], s = ov[2 * i + 1];
        for (int ch = 0; ch < IN_CH; ch++)
            atomicAdd(&agg1[d * 16 + ch], x[s * IN_CH + ch]);
    }
}

// ---------------- layer 1 dense: h1 = relu(Wl1*mean + Wr1*x + b) -> fp16 ------
__global__ void k_dense1(const float* __restrict__ x, const float* __restrict__ agg1,
                         const int* __restrict__ cnt, const float* __restrict__ Wl,
                         const float* __restrict__ bl, const float* __restrict__ Wr,
                         unsigned* __restrict__ h1h, int N) {
    int lane = threadIdx.x & 63;
    int n = blockIdx.x * 4 + (threadIdx.x >> 6);
    if (n > N) return;
    if (n == N) {
        if (lane < 32) h1h[n * 32 + lane] = 0u;
        return;
    }
    int deg = cnt[n];
    float inv = deg > 0 ? 1.f / (float)deg : 0.f;
    float mv = (lane < 16) ? agg1[n * 16 + lane] * inv : 0.f;
    float xv = (lane < IN_CH) ? x[n * IN_CH + lane] : 0.f;
    float h = bl[lane];
    #pragma unroll
    for (int c = 0; c < IN_CH; c++)
        h += Wl[lane * IN_CH + c] * __shfl(mv, c) + Wr[lane * IN_CH + c] * __shfl(xv, c);
    h = fmaxf(h, 0.f);
    unsigned my = (unsigned)__half_as_ushort(__float2half_rn(h));
    unsigned nx = __shfl_down(my, 1);
    if ((lane & 1) == 0) h1h[n * 32 + (lane >> 1)] = my | (nx << 16);
}

// ---------------- layer 2 aggregate: sum of h1 (fp16) rows -> fp32 ------------
__device__ __forceinline__ void add_h2(float& a0, float& a1, unsigned u) {
    __half2 h = *(__half2*)&u;
    float2 f = __half22float2(h);
    a0 += f.x; a1 += f.y;
}

__global__ void k_agg2(const uint4* __restrict__ h1h4, const int* __restrict__ col64,
                       float* __restrict__ agg2, int N) {
    int lane = threadIdx.x & 63;
    int n = blockIdx.x * 4 + (threadIdx.x >> 6);
    if (n >= N) return;
    int c8 = lane & 7, sub = lane >> 3;
    const int* cb = col64 + n * PAD;
    int s[8];
    #pragma unroll
    for (int jj = 0; jj < 8; jj++) s[jj] = cb[sub + 8 * jj];
    uint4 v[8];
    #pragma unroll
    for (int jj = 0; jj < 8; jj++) v[jj] = h1h4[s[jj] * 8 + c8];
    float acc[8];
    #pragma unroll
    for (int t = 0; t < 8; t++) acc[t] = 0.f;
    #pragma unroll
    for (int jj = 0; jj < 8; jj++) {
        add_h2(acc[0], acc[1], v[jj].x);
        add_h2(acc[2], acc[3], v[jj].y);
        add_h2(acc[4], acc[5], v[jj].z);
        add_h2(acc[6], acc[7], v[jj].w);
    }
    #pragma unroll
    for (int off = 8; off <= 32; off <<= 1) {
        #pragma unroll
        for (int t = 0; t < 8; t++) acc[t] += __shfl_xor(acc[t], off);
    }
    float val = acc[0];                        // channel = 8*c8 + sub
    #pragma unroll
    for (int t = 1; t < 8; t++) if (sub == t) val = acc[t];
    agg2[n * 64 + 8 * c8 + sub] = val;
}

__global__ void k_ov2(const int* __restrict__ ovcnt, const int* __restrict__ ov,
                      const unsigned* __restrict__ h1h, float* __restrict__ agg2) {
    int c = *ovcnt; if (c > OVCAP) c = OVCAP;
    const __half* h1 = (const __half*)h1h;
    for (int i = blockIdx.x * blockDim.x + threadIdx.x; i < c;
         i += gridDim.x * blockDim.x) {
        int d = ov[2 * i], s = ov[2 * i + 1];
        for (int ch = 0; ch < HID; ch++)
            atomicAdd(&agg2[d * 64 + ch], __half2float(h1[s * 64 + ch]));
    }
}

// ---------------- mean16 = fp16(agg2 / deg) ----------------
__global__ void k_mean2(const float2* __restrict__ agg2_2, const int* __restrict__ cnt,
                        unsigned* __restrict__ mean16, int N) {
    int i = blockIdx.x * blockDim.x + threadIdx.x;   // one uint = 2 channels
    if (i >= N * 32) return;
    int n = i >> 5;
    int deg = cnt[n];
    float inv = deg > 0 ? 1.f / (float)deg : 0.f;
    float2 v = agg2_2[i];
    unsigned lo = (unsigned)__half_as_ushort(__float2half_rn(v.x * inv));
    unsigned hi = (unsigned)__half_as_ushort(__float2half_rn(v.y * inv));
    mean16[i] = lo | (hi << 16);
}

// ---- layer 2 dense as MFMA GEMM: out = Wlin*relu([mean|h1]@[Wl2|Wr2]^T+b)+blin
__global__ __launch_bounds__(256) void k_dense2(
    const uint4* __restrict__ mean16_u4, const uint4* __restrict__ h1h_u4,
    const __half* __restrict__ wl2h, const __half* __restrict__ wr2h,
    const float* __restrict__ bl, const float* __restrict__ Wlin,
    const float* __restrict__ blin, float* __restrict__ out, int N) {
    union U { uint4 u; half8_t h; };
    int lane = threadIdx.x & 63;
    int wave = blockIdx.x * 4 + (threadIdx.x >> 6);
    int nwaves = gridDim.x * 4;
    int r16 = lane & 15, quad = lane >> 4;
    const uint4* wlu = (const uint4*)wl2h;   // row = 8 x uint4
    const uint4* wru = (const uint4*)wr2h;
    half8_t bfr[4][4];                       // [out-tile][k-step]
    #pragma unroll
    for (int tt = 0; tt < 4; tt++) {
        int o = tt * 16 + r16;               // B[k][n]: lane holds out col o
        U t0, t1, t2, t3;
        t0.u = wlu[o * 8 + quad];            // ch  0..31
        t1.u = wlu[o * 8 + 4 + quad];        // ch 32..63
        t2.u = wru[o * 8 + quad];            // ch 64..95
        t3.u = wru[o * 8 + 4 + quad];        // ch 96..127
        bfr[tt][0] = t0.h; bfr[tt][1] = t1.h; bfr[tt][2] = t2.h; bfr[tt][3] = t3.h;
    }
    float bl_c[4], wl_c[4];
    #pragma unroll
    for (int tt = 0; tt < 4; tt++) {
        bl_c[tt] = bl[tt * 16 + r16];
        wl_c[tt] = Wlin[tt * 16 + r16];
    }
    float b0 = blin[0];
    int ntiles = (N + 15) >> 4;
    for (int t = wave; t < ntiles; t += nwaves) {
        int nb = t * 16;
        int n = nb + r16; if (n >= N) n = N - 1;     // clamp: reads only
        U a0, a1, a2, a3;                            // A[m][k]: lane holds row n
        a0.u = mean16_u4[n * 8 + quad];
        a1.u = mean16_u4[n * 8 + 4 + quad];
        a2.u = h1h_u4[n * 8 + quad];
        a3.u = h1h_u4[n * 8 + 4 + quad];
        float p0 = 0.f, p1 = 0.f, p2 = 0.f, p3 = 0.f;
        #pragma unroll
        for (int tt = 0; tt < 4; tt++) {
            f32x4_t c = {0.f, 0.f, 0.f, 0.f};
            c = __builtin_amdgcn_mfma_f32_16x16x32_f16(a0.h, bfr[tt][0], c, 0, 0, 0);
            c = __builtin_amdgcn_mfma_f32_16x16x32_f16(a1.h, bfr[tt][1], c, 0, 0, 0);
            c = __builtin_amdgcn_mfma_f32_16x16x32_f16(a2.h, bfr[tt][2], c, 0, 0, 0);
            c = __builtin_amdgcn_mfma_f32_16x16x32_f16(a3.h, bfr[tt][3], c, 0, 0, 0);
            p0 += fmaxf(c[0] + bl_c[tt], 0.f) * wl_c[tt];
            p1 += fmaxf(c[1] + bl_c[tt], 0.f) * wl_c[tt];
            p2 += fmaxf(c[2] + bl_c[tt], 0.f) * wl_c[tt];
            p3 += fmaxf(c[3] + bl_c[tt], 0.f) * wl_c[tt];
        }
        #pragma unroll
        for (int off = 1; off <= 8; off <<= 1) {
            p0 += __shfl_xor(p0, off); p1 += __shfl_xor(p1, off);
            p2 += __shfl_xor(p2, off); p3 += __shfl_xor(p3, off);
        }
        if (r16 == 0) {
            int nn = nb + quad * 4;
            if (nn + 3 < N) {
                ((float4*)out)[nn >> 2] = make_float4(p0 + b0, p1 + b0, p2 + b0, p3 + b0);
            } else {
                if (nn + 0 < N) out[nn + 0] = p0 + b0;
                if (nn + 1 < N) out[nn + 1] = p1 + b0;
                if (nn + 2 < N) out[nn + 2] = p2 + b0;
                if (nn + 3 < N) out[nn + 3] = p3 + b0;
            }
        }
    }
}

// ---------------- launch ----------------

extern "C" void kernel_launch(void* const* d_in, const int* in_sizes, int n_in,
                              void* d_out, int out_size, void* d_ws, size_t ws_size,
                              hipStream_t stream) {
    const float* x    = (const float*)d_in[0];
    const int*   ei   = (const int*)d_in[1];
    const float* Wl1  = (const float*)d_in[2];
    const float* bl1  = (const float*)d_in[3];
    const float* Wr1  = (const float*)d_in[4];
    const float* Wl2  = (const float*)d_in[5];
    const float* bl2  = (const float*)d_in[6];
    const float* Wr2  = (const float*)d_in[7];
    const float* Wlin = (const float*)d_in[8];
    const float* blin = (const float*)d_in[9];
    float* out = (float*)d_out;

    int N = in_sizes[0] / IN_CH;   // 100000
    int E = in_sizes[1] / 2;       // 3200000
    const int* srcp = ei;
    const int* dstp = ei + E;

    // workspace layout (int offsets; ~64.5 MB):
    //  cnt    @ 0          (N+1; cnt[N] = overflow counter)
    //  col64  @ 100,032    (N*64) — mean16 overlays first half (col64 dead
    //                               after k_agg2; k_mean2 runs after k_ov2)
    //  R      @ 6,500,032  (6,400,064): early = xp|agg1; late = agg2
    //  h1h    @ 12,900,096 ((N+1)*32)
    //  ov     @ 16,100,128 (2*OVCAP)
    //  wl2h   @ 16,132,896 (2048), wr2h @ 16,134,944 (2048)
    int* ws       = (int*)d_ws;
    int* cnt      = ws;
    int* ovcnt    = ws + N;
    int* col64    = ws + 100032;
    unsigned* mean16 = (unsigned*)(ws + 100032);     // overlays col64
    float* xp     = (float*)(ws + 6500032);          // dead after k_agg1
    float* agg1   = (float*)(ws + 8100064);          // dead after k_dense1
    float* agg2   = (float*)(ws + 6500032);          // overlays xp/agg1
    unsigned* h1h = (unsigned*)(ws + 12900096);
    int* ov       = ws + 16100128;
    __half* wl2h  = (__half*)(ws + 16132896);
    __half* wr2h  = (__half*)(ws + 16134944);

    hipMemsetAsync(cnt, 0, (size_t)(N + 1) * sizeof(int), stream);

    int eb = (E + 255) / 256;

    k_cvtw   <<<(HID * HID + 255) / 256, 256, 0, stream>>>(Wl2, Wr2, wl2h, wr2h);
    k_copyx  <<<((N + 1) * 16 + 255) / 256, 256, 0, stream>>>(x, xp, N);
    k_fillpad<<<(N * 16 + 255) / 256, 256, 0, stream>>>((int4*)col64, N * 16, N);
    k_build  <<<eb, 256, 0, stream>>>(srcp, dstp, cnt, col64, ovcnt, ov, E);

    k_agg1   <<<(N + 3) / 4, 256, 0, stream>>>((const float4*)xp, col64,
                                               (float4*)agg1, N);
    k_ov1    <<<8, 256, 0, stream>>>(ovcnt, ov, x, agg1);
    k_dense1 <<<(N + 4) / 4, 256, 0, stream>>>(x, agg1, cnt, Wl1, bl1, Wr1, h1h, N);

    k_agg2   <<<(N + 3) / 4, 256, 0, stream>>>((const uint4*)h1h, col64, agg2, N);
    k_ov2    <<<8, 256, 0, stream>>>(ovcnt, ov, h1h, agg2);
    k_mean2  <<<(N * 32 + 255) / 256, 256, 0, stream>>>((const float2*)agg2, cnt,
                                                        mean16, N);

    k_dense2 <<<512, 256, 0, stream>>>((const uint4*)mean16, (const uint4*)h1h,
                                       wl2h, wr2h, bl2, Wlin, blin, out, N);
}

// Round 7
// 371.882 us; speedup vs baseline: 1.3917x; 1.3917x over previous
//
#include <hip/hip_runtime.h>
#include <hip/hip_fp16.h>

#define IN_CH 11
#define HID 64
#define PAD 64
#define OVCAP 16384
#define NBLK 256
#define BSH 9           // bucket = dst >> 9 (512 nodes/bucket)

typedef _Float16 half8_t __attribute__((ext_vector_type(8)));
typedef float f32x4_t __attribute__((ext_vector_type(4)));

// ---------------- setup kernels ----------------

__global__ void k_copyx(const float* __restrict__ x, float* __restrict__ xp, int N) {
    int i = blockIdx.x * blockDim.x + threadIdx.x;
    if (i < (N + 1) * 16) {
        int row = i >> 4, c = i & 15;
        xp[i] = (row < N && c < IN_CH) ? x[row * IN_CH + c] : 0.f;
    }
}

__global__ void k_fillpad(int4* __restrict__ col4, int n4, int N) {
    int i = blockIdx.x * blockDim.x + threadIdx.x;
    if (i < n4) col4[i] = make_int4(N, N, N, N);
}

// fp32 weights (64x64) -> fp16, row-major
__global__ void k_cvtw(const float* __restrict__ Wl2, const float* __restrict__ Wr2,
                       __half* __restrict__ wl2h, __half* __restrict__ wr2h) {
    int i = blockIdx.x * blockDim.x + threadIdx.x;
    if (i < HID * HID) {
        wl2h[i] = __float2half_rn(Wl2[i]);
        wr2h[i] = __float2half_rn(Wr2[i]);
    }
}

// ---------------- CSR build: two-level counting sort, no global atomics -------

// pass A: per-chunk LDS histogram over coarse buckets; transposed store
__global__ __launch_bounds__(256) void k_hist(const int* __restrict__ dst,
        int* __restrict__ hist, int E, int csz, int nbkt) {
    __shared__ int h[256];
    int tid = threadIdx.x, blk = blockIdx.x;
    h[tid] = 0;
    __syncthreads();
    int c0 = blk * csz, c1 = min(c0 + csz, E);
    for (int e = c0 + tid; e < c1; e += 256)
        atomicAdd(&h[dst[e] >> BSH], 1);
    __syncthreads();
    if (tid < nbkt) hist[tid * NBLK + blk] = h[tid];
}

// pass B: single-block exclusive scan of the nbkt*NBLK table (in place) +
// bucket starts/counts
__global__ __launch_bounds__(1024) void k_scanhist(int* __restrict__ hist,
        int* __restrict__ bstart, int* __restrict__ bcount,
        int total, int nbkt, int E) {
    __shared__ int wsum[16];
    int tid = threadIdx.x;
    int lane = tid & 63, wv = tid >> 6;
    int L = (total + 1023) >> 10;
    int s0 = tid * L, s1 = min(s0 + L, total);
    int sum = 0;
    for (int i = s0; i < s1; i++) sum += hist[i];
    int inc = sum;
    for (int off = 1; off < 64; off <<= 1) {
        int t = __shfl_up(inc, off);
        if (lane >= off) inc += t;
    }
    if (lane == 63) wsum[wv] = inc;
    __syncthreads();
    if (wv == 0 && lane < 16) {
        int v = wsum[lane];
        int w = v;
        for (int off = 1; off < 16; off <<= 1) {
            int t = __shfl_up(w, off);
            if (lane >= off) w += t;
        }
        wsum[lane] = w - v;          // exclusive wave base
    }
    __syncthreads();
    int run = wsum[wv] + (inc - sum);
    for (int i = s0; i < s1; i++) {
        int v = hist[i];
        hist[i] = run;
        run += v;
    }
    __syncthreads();
    if (tid < nbkt) {
        int st = hist[tid * NBLK];
        bstart[tid] = st;
        bcount[tid] = ((tid + 1 < nbkt) ? hist[(tid + 1) * NBLK] : E) - st;
    }
}

// pass C: scatter (dst,src) pairs into bucket-grouped ebuf via LDS cursors
__global__ __launch_bounds__(256) void k_scatter(const int* __restrict__ src,
        const int* __restrict__ dst, const int* __restrict__ hist,
        int2* __restrict__ ebuf, int E, int csz, int nbkt) {
    __shared__ int cur[256];
    int tid = threadIdx.x, blk = blockIdx.x;
    if (tid < nbkt) cur[tid] = hist[tid * NBLK + blk];
    __syncthreads();
    int c0 = blk * csz, c1 = min(c0 + csz, E);
    for (int e = c0 + tid; e < c1; e += 256) {
        int d = dst[e], s = src[e];
        int slot = atomicAdd(&cur[d >> BSH], 1);
        ebuf[slot] = make_int2(d, s);
    }
}

// pass D: per-bucket rank via LDS atomics; write col64 + cnt (L2-local region)
__global__ __launch_bounds__(1024) void k_bbuild(const int2* __restrict__ ebuf,
        const int* __restrict__ bstart, const int* __restrict__ bcount,
        int* __restrict__ cnt, int* __restrict__ col64,
        int* __restrict__ ovcnt, int* __restrict__ ov, int N) {
    __shared__ int lc[512];
    int tid = threadIdx.x, b = blockIdx.x;
    int lo = b << BSH, hi = min(lo + 512, N);
    if (tid < 512) lc[tid] = 0;
    __syncthreads();
    int cs = bstart[b], cc = bcount[b];
    for (int i = tid; i < cc; i += 1024) {
        int2 p = ebuf[cs + i];
        int r = atomicAdd(&lc[p.x - lo], 1);
        if (r < PAD) {
            col64[p.x * PAD + r] = p.y;
        } else {
            int q = atomicAdd(ovcnt, 1);
            if (q < OVCAP) { ov[2 * q] = p.x; ov[2 * q + 1] = p.y; }
        }
    }
    __syncthreads();
    for (int i = tid; i < hi - lo; i += 1024) cnt[lo + i] = lc[i];
}

// ---------------- layer 1 aggregate: sum of x rows (fp32) ----------------
__global__ void k_agg1(const float4* __restrict__ xp4, const int* __restrict__ col64,
                       float4* __restrict__ agg14, int N) {
    int lane = threadIdx.x & 63;
    int n = blockIdx.x * 4 + (threadIdx.x >> 6);
    if (n >= N) return;
    int c4 = lane & 3, sub = lane >> 2;
    const int* cb = col64 + n * PAD;
    int s[4];
    #pragma unroll
    for (int jj = 0; jj < 4; jj++) s[jj] = cb[sub + 16 * jj];
    float4 v[4];
    #pragma unroll
    for (int jj = 0; jj < 4; jj++) v[jj] = xp4[s[jj] * 4 + c4];
    float4 a;
    a.x = (v[0].x + v[1].x) + (v[2].x + v[3].x);
    a.y = (v[0].y + v[1].y) + (v[2].y + v[3].y);
    a.z = (v[0].z + v[1].z) + (v[2].z + v[3].z);
    a.w = (v[0].w + v[1].w) + (v[2].w + v[3].w);
    #pragma unroll
    for (int off = 4; off <= 32; off <<= 1) {
        a.x += __shfl_xor(a.x, off); a.y += __shfl_xor(a.y, off);
        a.z += __shfl_xor(a.z, off); a.w += __shfl_xor(a.w, off);
    }
    if (lane < 4) agg14[n * 4 + lane] = a;
}

__global__ void k_ov1(const int* __restrict__ ovcnt, const int* __restrict__ ov,
                      const float* __restrict__ x, float* __restrict__ agg1) {
    int c = *ovcnt; if (c > OVCAP) c = OVCAP;
    for (int i = blockIdx.x * blockDim.x + threadIdx.x; i < c;
         i += gridDim.x * blockDim.x) {
        int d = ov[2 * i], s = ov[2 * i + 1];
        for (int ch = 0; ch < IN_CH; ch++)
            atomicAdd(&agg1[d * 16 + ch], x[s * IN_CH + ch]);
    }
}

// ---------------- layer 1 dense: h1 = relu(Wl1*mean + Wr1*x + b) -> fp16 ------
__global__ void k_dense1(const float* __restrict__ x, const float* __restrict__ agg1,
                         const int* __restrict__ cnt, const float* __restrict__ Wl,
                         const float* __restrict__ bl, const float* __restrict__ Wr,
                         unsigned* __restrict__ h1h, int N) {
    int lane = threadIdx.x & 63;
    int n = blockIdx.x * 4 + (threadIdx.x >> 6);
    if (n > N) return;
    if (n == N) {
        if (lane < 32) h1h[n * 32 + lane] = 0u;
        return;
    }
    int deg = cnt[n];
    float inv = deg > 0 ? 1.f / (float)deg : 0.f;
    float mv = (lane < 16) ? agg1[n * 16 + lane] * inv : 0.f;
    float xv = (lane < IN_CH) ? x[n * IN_CH + lane] : 0.f;
    float h = bl[lane];
    #pragma unroll
    for (int c = 0; c < IN_CH; c++)
        h += Wl[lane * IN_CH + c] * __shfl(mv, c) + Wr[lane * IN_CH + c] * __shfl(xv, c);
    h = fmaxf(h, 0.f);
    unsigned my = (unsigned)__half_as_ushort(__float2half_rn(h));
    unsigned nx = __shfl_down(my, 1);
    if ((lane & 1) == 0) h1h[n * 32 + (lane >> 1)] = my | (nx << 16);
}

// ---------------- layer 2 aggregate: sum of h1 (fp16) rows -> fp32 ------------
__device__ __forceinline__ void add_h2(float& a0, float& a1, unsigned u) {
    __half2 h = *(__half2*)&u;
    float2 f = __half22float2(h);
    a0 += f.x; a1 += f.y;
}

__global__ void k_agg2(const uint4* __restrict__ h1h4, const int* __restrict__ col64,
                       float* __restrict__ agg2, int N) {
    int lane = threadIdx.x & 63;
    int n = blockIdx.x * 4 + (threadIdx.x >> 6);
    if (n >= N) return;
    int c8 = lane & 7, sub = lane >> 3;
    const int* cb = col64 + n * PAD;
    int s[8];
    #pragma unroll
    for (int jj = 0; jj < 8; jj++) s[jj] = cb[sub + 8 * jj];
    uint4 v[8];
    #pragma unroll
    for (int jj = 0; jj < 8; jj++) v[jj] = h1h4[s[jj] * 8 + c8];
    float acc[8];
    #pragma unroll
    for (int t = 0; t < 8; t++) acc[t] = 0.f;
    #pragma unroll
    for (int jj = 0; jj < 8; jj++) {
        add_h2(acc[0], acc[1], v[jj].x);
        add_h2(acc[2], acc[3], v[jj].y);
        add_h2(acc[4], acc[5], v[jj].z);
        add_h2(acc[6], acc[7], v[jj].w);
    }
    #pragma unroll
    for (int off = 8; off <= 32; off <<= 1) {
        #pragma unroll
        for (int t = 0; t < 8; t++) acc[t] += __shfl_xor(acc[t], off);
    }
    float val = acc[0];                        // channel = 8*c8 + sub
    #pragma unroll
    for (int t = 1; t < 8; t++) if (sub == t) val = acc[t];
    agg2[n * 64 + 8 * c8 + sub] = val;
}

__global__ void k_ov2(const int* __restrict__ ovcnt, const int* __restrict__ ov,
                      const unsigned* __restrict__ h1h, float* __restrict__ agg2) {
    int c = *ovcnt; if (c > OVCAP) c = OVCAP;
    const __half* h1 = (const __half*)h1h;
    for (int i = blockIdx.x * blockDim.x + threadIdx.x; i < c;
         i += gridDim.x * blockDim.x) {
        int d = ov[2 * i], s = ov[2 * i + 1];
        for (int ch = 0; ch < HID; ch++)
            atomicAdd(&agg2[d * 64 + ch], __half2float(h1[s * 64 + ch]));
    }
}

// ---------------- mean16 = fp16(agg2 / deg) ----------------
__global__ void k_mean2(const float2* __restrict__ agg2_2, const int* __restrict__ cnt,
                        unsigned* __restrict__ mean16, int N) {
    int i = blockIdx.x * blockDim.x + threadIdx.x;   // one uint = 2 channels
    if (i >= N * 32) return;
    int n = i >> 5;
    int deg = cnt[n];
    float inv = deg > 0 ? 1.f / (float)deg : 0.f;
    float2 v = agg2_2[i];
    unsigned lo = (unsigned)__half_as_ushort(__float2half_rn(v.x * inv));
    unsigned hi = (unsigned)__half_as_ushort(__float2half_rn(v.y * inv));
    mean16[i] = lo | (hi << 16);
}

// ---- layer 2 dense as MFMA GEMM: out = Wlin*relu([mean|h1]@[Wl2|Wr2]^T+b)+blin
__global__ __launch_bounds__(256) void k_dense2(
    const uint4* __restrict__ mean16_u4, const uint4* __restrict__ h1h_u4,
    const __half* __restrict__ wl2h, const __half* __restrict__ wr2h,
    const float* __restrict__ bl, const float* __restrict__ Wlin,
    const float* __restrict__ blin, float* __restrict__ out, int N) {
    union U { uint4 u; half8_t h; };
    int lane = threadIdx.x & 63;
    int wave = blockIdx.x * 4 + (threadIdx.x >> 6);
    int nwaves = gridDim.x * 4;
    int r16 = lane & 15, quad = lane >> 4;
    const uint4* wlu = (const uint4*)wl2h;
    const uint4* wru = (const uint4*)wr2h;
    half8_t bfr[4][4];
    #pragma unroll
    for (int tt = 0; tt < 4; tt++) {
        int o = tt * 16 + r16;
        U t0, t1, t2, t3;
        t0.u = wlu[o * 8 + quad];
        t1.u = wlu[o * 8 + 4 + quad];
        t2.u = wru[o * 8 + quad];
        t3.u = wru[o * 8 + 4 + quad];
        bfr[tt][0] = t0.h; bfr[tt][1] = t1.h; bfr[tt][2] = t2.h; bfr[tt][3] = t3.h;
    }
    float bl_c[4], wl_c[4];
    #pragma unroll
    for (int tt = 0; tt < 4; tt++) {
        bl_c[tt] = bl[tt * 16 + r16];
        wl_c[tt] = Wlin[tt * 16 + r16];
    }
    float b0 = blin[0];
    int ntiles = (N + 15) >> 4;
    for (int t = wave; t < ntiles; t += nwaves) {
        int nb = t * 16;
        int n = nb + r16; if (n >= N) n = N - 1;
        U a0, a1, a2, a3;
        a0.u = mean16_u4[n * 8 + quad];
        a1.u = mean16_u4[n * 8 + 4 + quad];
        a2.u = h1h_u4[n * 8 + quad];
        a3.u = h1h_u4[n * 8 + 4 + quad];
        float p0 = 0.f, p1 = 0.f, p2 = 0.f, p3 = 0.f;
        #pragma unroll
        for (int tt = 0; tt < 4; tt++) {
            f32x4_t c = {0.f, 0.f, 0.f, 0.f};
            c = __builtin_amdgcn_mfma_f32_16x16x32_f16(a0.h, bfr[tt][0], c, 0, 0, 0);
            c = __builtin_amdgcn_mfma_f32_16x16x32_f16(a1.h, bfr[tt][1], c, 0, 0, 0);
            c = __builtin_amdgcn_mfma_f32_16x16x32_f16(a2.h, bfr[tt][2], c, 0, 0, 0);
            c = __builtin_amdgcn_mfma_f32_16x16x32_f16(a3.h, bfr[tt][3], c, 0, 0, 0);
            p0 += fmaxf(c[0] + bl_c[tt], 0.f) * wl_c[tt];
            p1 += fmaxf(c[1] + bl_c[tt], 0.f) * wl_c[tt];
            p2 += fmaxf(c[2] + bl_c[tt], 0.f) * wl_c[tt];
            p3 += fmaxf(c[3] + bl_c[tt], 0.f) * wl_c[tt];
        }
        #pragma unroll
        for (int off = 1; off <= 8; off <<= 1) {
            p0 += __shfl_xor(p0, off); p1 += __shfl_xor(p1, off);
            p2 += __shfl_xor(p2, off); p3 += __shfl_xor(p3, off);
        }
        if (r16 == 0) {
            int nn = nb + quad * 4;
            if (nn + 3 < N) {
                ((float4*)out)[nn >> 2] = make_float4(p0 + b0, p1 + b0, p2 + b0, p3 + b0);
            } else {
                if (nn + 0 < N) out[nn + 0] = p0 + b0;
                if (nn + 1 < N) out[nn + 1] = p1 + b0;
                if (nn + 2 < N) out[nn + 2] = p2 + b0;
                if (nn + 3 < N) out[nn + 3] = p3 + b0;
            }
        }
    }
}

// ---------------- launch ----------------

extern "C" void kernel_launch(void* const* d_in, const int* in_sizes, int n_in,
                              void* d_out, int out_size, void* d_ws, size_t ws_size,
                              hipStream_t stream) {
    const float* x    = (const float*)d_in[0];
    const int*   ei   = (const int*)d_in[1];
    const float* Wl1  = (const float*)d_in[2];
    const float* bl1  = (const float*)d_in[3];
    const float* Wr1  = (const float*)d_in[4];
    const float* Wl2  = (const float*)d_in[5];
    const float* bl2  = (const float*)d_in[6];
    const float* Wr2  = (const float*)d_in[7];
    const float* Wlin = (const float*)d_in[8];
    const float* blin = (const float*)d_in[9];
    float* out = (float*)d_out;

    int N = in_sizes[0] / IN_CH;   // 100000
    int E = in_sizes[1] / 2;       // 3200000
    const int* srcp = ei;
    const int* dstp = ei + E;

    // workspace layout (int offsets; ~64.8 MB):
    //  cnt    @ 0          (N+1; cnt[N] = overflow counter)
    //  col64  @ 100,032    (N*64) — mean16 overlays first half (dead after agg2)
    //  xp     @ 6,500,032  ((N+1)*16, dead after k_agg1)
    //  agg1   @ 8,100,064  (N*16, dead after k_dense1)
    //  ebuf   @ 9,700,064  (E int2 = 6.4M ints, dead after k_bbuild;
    //                       overlaps h1h tail — h1h written later)
    //  agg2   @ 6,500,032  (N*64, overlays xp/agg1/ebuf-head, live from k_agg2)
    //  h1h    @ 12,900,096 ((N+1)*32, written by k_dense1 after ebuf dies)
    //  ov     @ 16,100,128 (2*OVCAP)
    //  wl2h   @ 16,132,896 / wr2h @ 16,134,944 (2048 each)
    //  hist   @ 16,136,992 (nbkt*NBLK <= 65536)
    //  bstart @ 16,202,528 (256), bcount @ 16,202,784 (256)
    int* ws       = (int*)d_ws;
    int* cnt      = ws;
    int* ovcnt    = ws + N;
    int* col64    = ws + 100032;
    unsigned* mean16 = (unsigned*)(ws + 100032);
    float* xp     = (float*)(ws + 6500032);
    float* agg1   = (float*)(ws + 8100064);
    int2* ebuf    = (int2*)(ws + 9700064);
    float* agg2   = (float*)(ws + 6500032);
    unsigned* h1h = (unsigned*)(ws + 12900096);
    int* ov       = ws + 16100128;
    __half* wl2h  = (__half*)(ws + 16132896);
    __half* wr2h  = (__half*)(ws + 16134944);
    int* hist     = ws + 16136992;
    int* bstart   = ws + 16202528;
    int* bcount   = ws + 16202784;

    hipMemsetAsync(ovcnt, 0, sizeof(int), stream);

    int nbkt = (N + 511) >> BSH;          // 196
    int csz  = (E + NBLK - 1) / NBLK;     // 12500
    int total = nbkt * NBLK;

    k_cvtw   <<<(HID * HID + 255) / 256, 256, 0, stream>>>(Wl2, Wr2, wl2h, wr2h);
    k_copyx  <<<((N + 1) * 16 + 255) / 256, 256, 0, stream>>>(x, xp, N);
    k_fillpad<<<(N * 16 + 255) / 256, 256, 0, stream>>>((int4*)col64, N * 16, N);

    k_hist   <<<NBLK, 256, 0, stream>>>(dstp, hist, E, csz, nbkt);
    k_scanhist<<<1, 1024, 0, stream>>>(hist, bstart, bcount, total, nbkt, E);
    k_scatter<<<NBLK, 256, 0, stream>>>(srcp, dstp, hist, ebuf, E, csz, nbkt);
    k_bbuild <<<nbkt, 1024, 0, stream>>>(ebuf, bstart, bcount, cnt, col64,
                                         ovcnt, ov, N);

    k_agg1   <<<(N + 3) / 4, 256, 0, stream>>>((const float4*)xp, col64,
                                               (float4*)agg1, N);
    k_ov1    <<<8, 256, 0, stream>>>(ovcnt, ov, x, agg1);
    k_dense1 <<<(N + 4) / 4, 256, 0, stream>>>(x, agg1, cnt, Wl1, bl1, Wr1, h1h, N);

    k_agg2   <<<(N + 3) / 4, 256, 0, stream>>>((const uint4*)h1h, col64, agg2, N);
    k_ov2    <<<8, 256, 0, stream>>>(ovcnt, ov, h1h, agg2);
    k_mean2  <<<(N * 32 + 255) / 256, 256, 0, stream>>>((const float2*)agg2, cnt,
                                                        mean16, N);

    k_dense2 <<<512, 256, 0, stream>>>((const uint4*)mean16, (const uint4*)h1h,
                                       wl2h, wr2h, bl2, Wlin, blin, out, N);
}

// Round 8
// 301.292 us; speedup vs baseline: 1.7177x; 1.2343x over previous
//
#include <hip/hip_runtime.h>
#include <hip/hip_fp16.h>

#define IN_CH 11
#define HID 64
#define PAD 64
#define OVCAP 16384
#define NBLK 256
#define BSH 9           // bucket = dst >> 9 (512 nodes/bucket)

typedef _Float16 half8_t __attribute__((ext_vector_type(8)));
typedef float f32x4_t __attribute__((ext_vector_type(4)));

// ---------------- setup kernels ----------------

__global__ void k_copyx(const float* __restrict__ x, float* __restrict__ xp, int N) {
    int i = blockIdx.x * blockDim.x + threadIdx.x;
    if (i < (N + 1) * 16) {
        int row = i >> 4, c = i & 15;
        xp[i] = (row < N && c < IN_CH) ? x[row * IN_CH + c] : 0.f;
    }
}

__global__ void k_fillpad(int4* __restrict__ col4, int n4, int N) {
    int i = blockIdx.x * blockDim.x + threadIdx.x;
    if (i < n4) col4[i] = make_int4(N, N, N, N);
}

// fp32 weights (64x64) -> fp16, row-major
__global__ void k_cvtw(const float* __restrict__ Wl2, const float* __restrict__ Wr2,
                       __half* __restrict__ wl2h, __half* __restrict__ wr2h) {
    int i = blockIdx.x * blockDim.x + threadIdx.x;
    if (i < HID * HID) {
        wl2h[i] = __float2half_rn(Wl2[i]);
        wr2h[i] = __float2half_rn(Wr2[i]);
    }
}

// ---------------- CSR build: two-level counting sort, no global atomics -------

// pass A: per-chunk LDS histogram over coarse buckets; transposed store
__global__ __launch_bounds__(256) void k_hist(const int* __restrict__ dst,
        int* __restrict__ hist, int E, int csz, int nbkt) {
    __shared__ int h[256];
    int tid = threadIdx.x, blk = blockIdx.x;
    h[tid] = 0;
    __syncthreads();
    int c0 = blk * csz, c1 = min(c0 + csz, E);
    for (int e = c0 + tid; e < c1; e += 256)
        atomicAdd(&h[dst[e] >> BSH], 1);
    __syncthreads();
    if (tid < nbkt) hist[tid * NBLK + blk] = h[tid];
}

// pass B1: per-bucket exclusive scan of its 256 chunk counts (in place) + total
__global__ __launch_bounds__(256) void k_scanA(int* __restrict__ hist,
        int* __restrict__ btot) {
    __shared__ int wsum[4];
    int b = blockIdx.x, tid = threadIdx.x;
    int lane = tid & 63, wv = tid >> 6;
    int v = hist[b * NBLK + tid];
    int inc = v;
    #pragma unroll
    for (int off = 1; off < 64; off <<= 1) {
        int t = __shfl_up(inc, off);
        if (lane >= off) inc += t;
    }
    if (lane == 63) wsum[wv] = inc;
    __syncthreads();
    int base = 0;
    #pragma unroll
    for (int w = 0; w < 4; w++) base += (w < wv) ? wsum[w] : 0;
    hist[b * NBLK + tid] = base + inc - v;    // bucket-local exclusive
    if (tid == 255) btot[b] = base + inc;     // bucket total
}

// pass B2: scan bucket totals -> bstart/bcount (nbkt <= 256)
__global__ __launch_bounds__(256) void k_scanB(const int* __restrict__ btot,
        int* __restrict__ bstart, int* __restrict__ bcount, int nbkt) {
    __shared__ int wsum[4];
    int tid = threadIdx.x;
    int lane = tid & 63, wv = tid >> 6;
    int v = (tid < nbkt) ? btot[tid] : 0;
    int inc = v;
    #pragma unroll
    for (int off = 1; off < 64; off <<= 1) {
        int t = __shfl_up(inc, off);
        if (lane >= off) inc += t;
    }
    if (lane == 63) wsum[wv] = inc;
    __syncthreads();
    int base = 0;
    #pragma unroll
    for (int w = 0; w < 4; w++) base += (w < wv) ? wsum[w] : 0;
    if (tid < nbkt) {
        bstart[tid] = base + inc - v;
        bcount[tid] = v;
    }
}

// pass C: scatter (dst,src) pairs into bucket-grouped ebuf via LDS cursors
// cursor = bucket-local chunk offset + bucket global start
__global__ __launch_bounds__(256) void k_scatter(const int* __restrict__ src,
        const int* __restrict__ dst, const int* __restrict__ hist,
        const int* __restrict__ bstart,
        int2* __restrict__ ebuf, int E, int csz, int nbkt) {
    __shared__ int cur[256];
    int tid = threadIdx.x, blk = blockIdx.x;
    if (tid < nbkt) cur[tid] = hist[tid * NBLK + blk] + bstart[tid];
    __syncthreads();
    int c0 = blk * csz, c1 = min(c0 + csz, E);
    for (int e = c0 + tid; e < c1; e += 256) {
        int d = dst[e], s = src[e];
        int slot = atomicAdd(&cur[d >> BSH], 1);
        ebuf[slot] = make_int2(d, s);
    }
}

// pass D: per-bucket rank via LDS atomics; write col64 + cnt (L2-local region)
__global__ __launch_bounds__(1024) void k_bbuild(const int2* __restrict__ ebuf,
        const int* __restrict__ bstart, const int* __restrict__ bcount,
        int* __restrict__ cnt, int* __restrict__ col64,
        int* __restrict__ ovcnt, int* __restrict__ ov, int N) {
    __shared__ int lc[512];
    int tid = threadIdx.x, b = blockIdx.x;
    int lo = b << BSH, hi = min(lo + 512, N);
    if (tid < 512) lc[tid] = 0;
    __syncthreads();
    int cs = bstart[b], cc = bcount[b];
    for (int i = tid; i < cc; i += 1024) {
        int2 p = ebuf[cs + i];
        int r = atomicAdd(&lc[p.x - lo], 1);
        if (r < PAD) {
            col64[p.x * PAD + r] = p.y;
        } else {
            int q = atomicAdd(ovcnt, 1);
            if (q < OVCAP) { ov[2 * q] = p.x; ov[2 * q + 1] = p.y; }
        }
    }
    __syncthreads();
    for (int i = tid; i < hi - lo; i += 1024) cnt[lo + i] = lc[i];
}

// ---------------- layer 1 aggregate: sum of x rows (fp32) ----------------
__global__ void k_agg1(const float4* __restrict__ xp4, const int* __restrict__ col64,
                       float4* __restrict__ agg14, int N) {
    int lane = threadIdx.x & 63;
    int n = blockIdx.x * 4 + (threadIdx.x >> 6);
    if (n >= N) return;
    int c4 = lane & 3, sub = lane >> 2;
    const int* cb = col64 + n * PAD;
    int s[4];
    #pragma unroll
    for (int jj = 0; jj < 4; jj++) s[jj] = cb[sub + 16 * jj];
    float4 v[4];
    #pragma unroll
    for (int jj = 0; jj < 4; jj++) v[jj] = xp4[s[jj] * 4 + c4];
    float4 a;
    a.x = (v[0].x + v[1].x) + (v[2].x + v[3].x);
    a.y = (v[0].y + v[1].y) + (v[2].y + v[3].y);
    a.z = (v[0].z + v[1].z) + (v[2].z + v[3].z);
    a.w = (v[0].w + v[1].w) + (v[2].w + v[3].w);
    #pragma unroll
    for (int off = 4; off <= 32; off <<= 1) {
        a.x += __shfl_xor(a.x, off); a.y += __shfl_xor(a.y, off);
        a.z += __shfl_xor(a.z, off); a.w += __shfl_xor(a.w, off);
    }
    if (lane < 4) agg14[n * 4 + lane] = a;
}

__global__ void k_ov1(const int* __restrict__ ovcnt, const int* __restrict__ ov,
                      const float* __restrict__ x, float* __restrict__ agg1) {
    int c = *ovcnt; if (c > OVCAP) c = OVCAP;
    for (int i = blockIdx.x * blockDim.x + threadIdx.x; i < c;
         i += gridDim.x * blockDim.x) {
        int d = ov[2 * i], s = ov[2 * i + 1];
        for (int ch = 0; ch < IN_CH; ch++)
            atomicAdd(&agg1[d * 16 + ch], x[s * IN_CH + ch]);
    }
}

// ---------------- layer 1 dense: h1 = relu(Wl1*mean + Wr1*x + b) -> fp16 ------
__global__ void k_dense1(const float* __restrict__ x, const float* __restrict__ agg1,
                         const int* __restrict__ cnt, const float* __restrict__ Wl,
                         const float* __restrict__ bl, const float* __restrict__ Wr,
                         unsigned* __restrict__ h1h, int N) {
    int lane = threadIdx.x & 63;
    int n = blockIdx.x * 4 + (threadIdx.x >> 6);
    if (n > N) return;
    if (n == N) {
        if (lane < 32) h1h[n * 32 + lane] = 0u;
        return;
    }
    int deg = cnt[n];
    float inv = deg > 0 ? 1.f / (float)deg : 0.f;
    float mv = (lane < 16) ? agg1[n * 16 + lane] * inv : 0.f;
    float xv = (lane < IN_CH) ? x[n * IN_CH + lane] : 0.f;
    float h = bl[lane];
    #pragma unroll
    for (int c = 0; c < IN_CH; c++)
        h += Wl[lane * IN_CH + c] * __shfl(mv, c) + Wr[lane * IN_CH + c] * __shfl(xv, c);
    h = fmaxf(h, 0.f);
    unsigned my = (unsigned)__half_as_ushort(__float2half_rn(h));
    unsigned nx = __shfl_down(my, 1);
    if ((lane & 1) == 0) h1h[n * 32 + (lane >> 1)] = my | (nx << 16);
}

// ---------------- layer 2 aggregate: sum of h1 (fp16) rows -> fp32 ------------
__device__ __forceinline__ void add_h2(float& a0, float& a1, unsigned u) {
    __half2 h = *(__half2*)&u;
    float2 f = __half22float2(h);
    a0 += f.x; a1 += f.y;
}

__global__ void k_agg2(const uint4* __restrict__ h1h4, const int* __restrict__ col64,
                       float* __restrict__ agg2, int N) {
    int lane = threadIdx.x & 63;
    int n = blockIdx.x * 4 + (threadIdx.x >> 6);
    if (n >= N) return;
    int c8 = lane & 7, sub = lane >> 3;
    const int* cb = col64 + n * PAD;
    int s[8];
    #pragma unroll
    for (int jj = 0; jj < 8; jj++) s[jj] = cb[sub + 8 * jj];
    uint4 v[8];
    #pragma unroll
    for (int jj = 0; jj < 8; jj++) v[jj] = h1h4[s[jj] * 8 + c8];
    float acc[8];
    #pragma unroll
    for (int t = 0; t < 8; t++) acc[t] = 0.f;
    #pragma unroll
    for (int jj = 0; jj < 8; jj++) {
        add_h2(acc[0], acc[1], v[jj].x);
        add_h2(acc[2], acc[3], v[jj].y);
        add_h2(acc[4], acc[5], v[jj].z);
        add_h2(acc[6], acc[7], v[jj].w);
    }
    #pragma unroll
    for (int off = 8; off <= 32; off <<= 1) {
        #pragma unroll
        for (int t = 0; t < 8; t++) acc[t] += __shfl_xor(acc[t], off);
    }
    float val = acc[0];                        // channel = 8*c8 + sub
    #pragma unroll
    for (int t = 1; t < 8; t++) if (sub == t) val = acc[t];
    agg2[n * 64 + 8 * c8 + sub] = val;
}

__global__ void k_ov2(const int* __restrict__ ovcnt, const int* __restrict__ ov,
                      const unsigned* __restrict__ h1h, float* __restrict__ agg2) {
    int c = *ovcnt; if (c > OVCAP) c = OVCAP;
    const __half* h1 = (const __half*)h1h;
    for (int i = blockIdx.x * blockDim.x + threadIdx.x; i < c;
         i += gridDim.x * blockDim.x) {
        int d = ov[2 * i], s = ov[2 * i + 1];
        for (int ch = 0; ch < HID; ch++)
            atomicAdd(&agg2[d * 64 + ch], __half2float(h1[s * 64 + ch]));
    }
}

// ---------------- mean16 = fp16(agg2 / deg) ----------------
__global__ void k_mean2(const float2* __restrict__ agg2_2, const int* __restrict__ cnt,
                        unsigned* __restrict__ mean16, int N) {
    int i = blockIdx.x * blockDim.x + threadIdx.x;   // one uint = 2 channels
    if (i >= N * 32) return;
    int n = i >> 5;
    int deg = cnt[n];
    float inv = deg > 0 ? 1.f / (float)deg : 0.f;
    float2 v = agg2_2[i];
    unsigned lo = (unsigned)__half_as_ushort(__float2half_rn(v.x * inv));
    unsigned hi = (unsigned)__half_as_ushort(__float2half_rn(v.y * inv));
    mean16[i] = lo | (hi << 16);
}

// ---- layer 2 dense as MFMA GEMM: out = Wlin*relu([mean|h1]@[Wl2|Wr2]^T+b)+blin
__global__ __launch_bounds__(256) void k_dense2(
    const uint4* __restrict__ mean16_u4, const uint4* __restrict__ h1h_u4,
    const __half* __restrict__ wl2h, const __half* __restrict__ wr2h,
    const float* __restrict__ bl, const float* __restrict__ Wlin,
    const float* __restrict__ blin, float* __restrict__ out, int N) {
    union U { uint4 u; half8_t h; };
    int lane = threadIdx.x & 63;
    int wave = blockIdx.x * 4 + (threadIdx.x >> 6);
    int nwaves = gridDim.x * 4;
    int r16 = lane & 15, quad = lane >> 4;
    const uint4* wlu = (const uint4*)wl2h;
    const uint4* wru = (const uint4*)wr2h;
    half8_t bfr[4][4];
    #pragma unroll
    for (int tt = 0; tt < 4; tt++) {
        int o = tt * 16 + r16;
        U t0, t1, t2, t3;
        t0.u = wlu[o * 8 + quad];
        t1.u = wlu[o * 8 + 4 + quad];
        t2.u = wru[o * 8 + quad];
        t3.u = wru[o * 8 + 4 + quad];
        bfr[tt][0] = t0.h; bfr[tt][1] = t1.h; bfr[tt][2] = t2.h; bfr[tt][3] = t3.h;
    }
    float bl_c[4], wl_c[4];
    #pragma unroll
    for (int tt = 0; tt < 4; tt++) {
        bl_c[tt] = bl[tt * 16 + r16];
        wl_c[tt] = Wlin[tt * 16 + r16];
    }
    float b0 = blin[0];
    int ntiles = (N + 15) >> 4;
    for (int t = wave; t < ntiles; t += nwaves) {
        int nb = t * 16;
        int n = nb + r16; if (n >= N) n = N - 1;
        U a0, a1, a2, a3;
        a0.u = mean16_u4[n * 8 + quad];
        a1.u = mean16_u4[n * 8 + 4 + quad];
        a2.u = h1h_u4[n * 8 + quad];
        a3.u = h1h_u4[n * 8 + 4 + quad];
        float p0 = 0.f, p1 = 0.f, p2 = 0.f, p3 = 0.f;
        #pragma unroll
        for (int tt = 0; tt < 4; tt++) {
            f32x4_t c = {0.f, 0.f, 0.f, 0.f};
            c = __builtin_amdgcn_mfma_f32_16x16x32_f16(a0.h, bfr[tt][0], c, 0, 0, 0);
            c = __builtin_amdgcn_mfma_f32_16x16x32_f16(a1.h, bfr[tt][1], c, 0, 0, 0);
            c = __builtin_amdgcn_mfma_f32_16x16x32_f16(a2.h, bfr[tt][2], c, 0, 0, 0);
            c = __builtin_amdgcn_mfma_f32_16x16x32_f16(a3.h, bfr[tt][3], c, 0, 0, 0);
            p0 += fmaxf(c[0] + bl_c[tt], 0.f) * wl_c[tt];
            p1 += fmaxf(c[1] + bl_c[tt], 0.f) * wl_c[tt];
            p2 += fmaxf(c[2] + bl_c[tt], 0.f) * wl_c[tt];
            p3 += fmaxf(c[3] + bl_c[tt], 0.f) * wl_c[tt];
        }
        #pragma unroll
        for (int off = 1; off <= 8; off <<= 1) {
            p0 += __shfl_xor(p0, off); p1 += __shfl_xor(p1, off);
            p2 += __shfl_xor(p2, off); p3 += __shfl_xor(p3, off);
        }
        if (r16 == 0) {
            int nn = nb + quad * 4;
            if (nn + 3 < N) {
                ((float4*)out)[nn >> 2] = make_float4(p0 + b0, p1 + b0, p2 + b0, p3 + b0);
            } else {
                if (nn + 0 < N) out[nn + 0] = p0 + b0;
                if (nn + 1 < N) out[nn + 1] = p1 + b0;
                if (nn + 2 < N) out[nn + 2] = p2 + b0;
                if (nn + 3 < N) out[nn + 3] = p3 + b0;
            }
        }
    }
}

// ---------------- launch ----------------

extern "C" void kernel_launch(void* const* d_in, const int* in_sizes, int n_in,
                              void* d_out, int out_size, void* d_ws, size_t ws_size,
                              hipStream_t stream) {
    const float* x    = (const float*)d_in[0];
    const int*   ei   = (const int*)d_in[1];
    const float* Wl1  = (const float*)d_in[2];
    const float* bl1  = (const float*)d_in[3];
    const float* Wr1  = (const float*)d_in[4];
    const float* Wl2  = (const float*)d_in[5];
    const float* bl2  = (const float*)d_in[6];
    const float* Wr2  = (const float*)d_in[7];
    const float* Wlin = (const float*)d_in[8];
    const float* blin = (const float*)d_in[9];
    float* out = (float*)d_out;

    int N = in_sizes[0] / IN_CH;   // 100000
    int E = in_sizes[1] / 2;       // 3200000
    const int* srcp = ei;
    const int* dstp = ei + E;

    // workspace layout (int offsets; ~64.8 MB):
    //  cnt    @ 0          (N+1; cnt[N] = overflow counter)
    //  col64  @ 100,032    (N*64) — mean16 overlays first half (dead after agg2)
    //  xp     @ 6,500,032  ((N+1)*16, dead after k_agg1)
    //  agg1   @ 8,100,064  (N*16, dead after k_dense1)
    //  ebuf   @ 9,700,064  (E int2, dead after k_bbuild)
    //  agg2   @ 6,500,032  (N*64, overlays xp/agg1/ebuf-head, live from k_agg2)
    //  h1h    @ 12,900,096 ((N+1)*32, written by k_dense1 after ebuf dies)
    //  ov     @ 16,100,128 (2*OVCAP)
    //  wl2h   @ 16,132,896 / wr2h @ 16,134,944 (2048 each)
    //  hist   @ 16,136,992 (nbkt*NBLK <= 65536)
    //  bstart @ 16,202,528 (256), bcount @ 16,202,784 (256), btot @ 16,203,040
    int* ws       = (int*)d_ws;
    int* cnt      = ws;
    int* ovcnt    = ws + N;
    int* col64    = ws + 100032;
    unsigned* mean16 = (unsigned*)(ws + 100032);
    float* xp     = (float*)(ws + 6500032);
    float* agg1   = (float*)(ws + 8100064);
    int2* ebuf    = (int2*)(ws + 9700064);
    float* agg2   = (float*)(ws + 6500032);
    unsigned* h1h = (unsigned*)(ws + 12900096);
    int* ov       = ws + 16100128;
    __half* wl2h  = (__half*)(ws + 16132896);
    __half* wr2h  = (__half*)(ws + 16134944);
    int* hist     = ws + 16136992;
    int* bstart   = ws + 16202528;
    int* bcount   = ws + 16202784;
    int* btot     = ws + 16203040;

    hipMemsetAsync(ovcnt, 0, sizeof(int), stream);

    int nbkt = (N + 511) >> BSH;          // 196
    int csz  = (E + NBLK - 1) / NBLK;     // 12500

    k_cvtw   <<<(HID * HID + 255) / 256, 256, 0, stream>>>(Wl2, Wr2, wl2h, wr2h);
    k_copyx  <<<((N + 1) * 16 + 255) / 256, 256, 0, stream>>>(x, xp, N);
    k_fillpad<<<(N * 16 + 255) / 256, 256, 0, stream>>>((int4*)col64, N * 16, N);

    k_hist   <<<NBLK, 256, 0, stream>>>(dstp, hist, E, csz, nbkt);
    k_scanA  <<<nbkt, 256, 0, stream>>>(hist, btot);
    k_scanB  <<<1, 256, 0, stream>>>(btot, bstart, bcount, nbkt);
    k_scatter<<<NBLK, 256, 0, stream>>>(srcp, dstp, hist, bstart, ebuf, E, csz, nbkt);
    k_bbuild <<<nbkt, 1024, 0, stream>>>(ebuf, bstart, bcount, cnt, col64,
                                         ovcnt, ov, N);

    k_agg1   <<<(N + 3) / 4, 256, 0, stream>>>((const float4*)xp, col64,
                                               (float4*)agg1, N);
    k_ov1    <<<8, 256, 0, stream>>>(ovcnt, ov, x, agg1);
    k_dense1 <<<(N + 4) / 4, 256, 0, stream>>>(x, agg1, cnt, Wl1, bl1, Wr1, h1h, N);

    k_agg2   <<<(N + 3) / 4, 256, 0, stream>>>((const uint4*)h1h, col64, agg2, N);
    k_ov2    <<<8, 256, 0, stream>>>(ovcnt, ov, h1h, agg2);
    k_mean2  <<<(N * 32 + 255) / 256, 256, 0, stream>>>((const float2*)agg2, cnt,
                                                        mean16, N);

    k_dense2 <<<512, 256, 0, stream>>>((const uint4*)mean16, (const uint4*)h1h,
                                       wl2h, wr2h, bl2, Wlin, blin, out, N);
}

// Round 9
// 283.029 us; speedup vs baseline: 1.8286x; 1.0645x over previous
//
#include <hip/hip_runtime.h>
#include <hip/hip_fp16.h>

#define IN_CH 11
#define HID 64
#define PAD 64
#define OVCAP 16384
#define NBLK 256
#define BSH 7            // bucket = dst >> 7 (128 nodes/bucket)

typedef _Float16 half8_t __attribute__((ext_vector_type(8)));
typedef float f32x4_t __attribute__((ext_vector_type(4)));

// ---- prep: x -> fp16 padded copy (stride 16, row N = 0), weights -> fp16,
//      ovcnt = 0. One kernel, one launch.
__global__ void k_prep(const float* __restrict__ x, const float* __restrict__ Wl2,
                       const float* __restrict__ Wr2, unsigned* __restrict__ xphu,
                       __half* __restrict__ wl2h, __half* __restrict__ wr2h,
                       int* __restrict__ ovcnt, int N) {
    int i = blockIdx.x * blockDim.x + threadIdx.x;
    if (i == 0) *ovcnt = 0;
    if (i < HID * HID) {
        wl2h[i] = __float2half_rn(Wl2[i]);
        wr2h[i] = __float2half_rn(Wr2[i]);
    }
    if (i < (N + 1) * 8) {               // one uint = 2 fp16 channels
        int n = i >> 3, j = (i & 7) * 2;
        float a = 0.f, b = 0.f;
        if (n < N) {
            if (j < IN_CH) a = x[n * IN_CH + j];
            if (j + 1 < IN_CH) b = x[n * IN_CH + j + 1];
        }
        unsigned lo = (unsigned)__half_as_ushort(__float2half_rn(a));
        unsigned hi = (unsigned)__half_as_ushort(__float2half_rn(b));
        xphu[i] = lo | (hi << 16);
    }
}

// ---------------- CSR build: counting sort, LDS-resident bucket image -------

__global__ __launch_bounds__(256) void k_hist(const int* __restrict__ dst,
        int* __restrict__ hist, int E, int csz, int nbkt) {
    __shared__ int h[800];
    int tid = threadIdx.x, blk = blockIdx.x;
    for (int t = tid; t < nbkt; t += 256) h[t] = 0;
    __syncthreads();
    int c0 = blk * csz, c1 = min(c0 + csz, E);
    for (int e = c0 + tid; e < c1; e += 256)
        atomicAdd(&h[dst[e] >> BSH], 1);
    __syncthreads();
    for (int t = tid; t < nbkt; t += 256) hist[t * NBLK + blk] = h[t];
}

// per-bucket exclusive scan of its 256 chunk counts (in place) + bucket total
__global__ __launch_bounds__(256) void k_scanA(int* __restrict__ hist,
        int* __restrict__ btot) {
    __shared__ int wsum[4];
    int b = blockIdx.x, tid = threadIdx.x;
    int lane = tid & 63, wv = tid >> 6;
    int v = hist[b * NBLK + tid];
    int inc = v;
    #pragma unroll
    for (int off = 1; off < 64; off <<= 1) {
        int t = __shfl_up(inc, off);
        if (lane >= off) inc += t;
    }
    if (lane == 63) wsum[wv] = inc;
    __syncthreads();
    int base = 0;
    #pragma unroll
    for (int w = 0; w < 4; w++) base += (w < wv) ? wsum[w] : 0;
    hist[b * NBLK + tid] = base + inc - v;
    if (tid == 255) btot[b] = base + inc;
}

// scan bucket totals -> bstart (nbkt <= 1024)
__global__ __launch_bounds__(1024) void k_scanB(const int* __restrict__ btot,
        int* __restrict__ bstart, int nbkt) {
    __shared__ int wsum[16];
    int tid = threadIdx.x;
    int lane = tid & 63, wv = tid >> 6;
    int v = (tid < nbkt) ? btot[tid] : 0;
    int inc = v;
    #pragma unroll
    for (int off = 1; off < 64; off <<= 1) {
        int t = __shfl_up(inc, off);
        if (lane >= off) inc += t;
    }
    if (lane == 63) wsum[wv] = inc;
    __syncthreads();
    int base = 0;
    #pragma unroll
    for (int w = 0; w < 16; w++) base += (w < wv) ? wsum[w] : 0;
    if (tid < nbkt) bstart[tid] = base + inc - v;
}

// scatter (dst,src) pairs into bucket-grouped ebuf via LDS cursors
__global__ __launch_bounds__(256) void k_scatter(const int* __restrict__ src,
        const int* __restrict__ dst, const int* __restrict__ hist,
        const int* __restrict__ bstart,
        int2* __restrict__ ebuf, int E, int csz, int nbkt) {
    __shared__ int cur[800];
    int tid = threadIdx.x, blk = blockIdx.x;
    for (int t = tid; t < nbkt; t += 256)
        cur[t] = hist[t * NBLK + blk] + bstart[t];
    __syncthreads();
    int c0 = blk * csz, c1 = min(c0 + csz, E);
    for (int e = c0 + tid; e < c1; e += 256) {
        int d = dst[e], s = src[e];
        int slot = atomicAdd(&cur[d >> BSH], 1);
        ebuf[slot] = make_int2(d, s);
    }
}

// per-bucket: build 128-node x 64-slot col image in LDS (pads included),
// stream out coalesced; write cnt. No separate fillpad pass.
__global__ __launch_bounds__(256) void k_bbuild(const int2* __restrict__ ebuf,
        const int* __restrict__ bstart, const int* __restrict__ btot,
        int* __restrict__ cnt, int* __restrict__ col64,
        int* __restrict__ ovcnt, int* __restrict__ ov, int N) {
    __shared__ int lc[128];
    __shared__ int colsh[128 * PAD];    // 32 KB
    int tid = threadIdx.x, b = blockIdx.x;
    int lo = b << BSH, hi = min(lo + 128, N);
    #pragma unroll
    for (int i = 0; i < 8; i++)
        ((int4*)colsh)[tid + i * 256] = make_int4(N, N, N, N);
    if (tid < 128) lc[tid] = 0;
    __syncthreads();
    int cs = bstart[b], cc = btot[b];
    for (int i = tid; i < cc; i += 256) {
        int2 p = ebuf[cs + i];
        int r = atomicAdd(&lc[p.x - lo], 1);
        if (r < PAD) {
            colsh[((p.x - lo) << 6) | r] = p.y;
        } else {
            int q = atomicAdd(ovcnt, 1);
            if (q < OVCAP) { ov[2 * q] = p.x; ov[2 * q + 1] = p.y; }
        }
    }
    __syncthreads();
    int nn = hi - lo;
    int4* dst4 = (int4*)col64 + (size_t)lo * 16;
    for (int i = tid; i < nn * 16; i += 256) dst4[i] = ((int4*)colsh)[i];
    if (tid < nn) cnt[lo + tid] = lc[tid];
}

// ---------------- layer 1 aggregate: sum of x rows (fp16 gather, pk adds) -----
__global__ void k_agg1(const unsigned* __restrict__ xphu,
                       const int* __restrict__ col64,
                       float* __restrict__ agg1, int N) {
    int lane = threadIdx.x & 63;
    int n = blockIdx.x * 4 + (threadIdx.x >> 6);
    if (n >= N) return;
    int c8 = lane & 7, sub = lane >> 3;      // 8 row slots x 8 uint lanes
    const int* cb = col64 + n * PAD;
    int s[8];
    #pragma unroll
    for (int jj = 0; jj < 8; jj++) s[jj] = cb[sub + 8 * jj];
    unsigned v[8];
    #pragma unroll
    for (int jj = 0; jj < 8; jj++) v[jj] = xphu[s[jj] * 8 + c8];
    __half2 a2 = __floats2half2_rn(0.f, 0.f);
    #pragma unroll
    for (int jj = 0; jj < 8; jj++) a2 = __hadd2(a2, *(__half2*)&v[jj]);
    float2 f = __half22float2(a2);
    #pragma unroll
    for (int off = 8; off <= 32; off <<= 1) {
        f.x += __shfl_xor(f.x, off);
        f.y += __shfl_xor(f.y, off);
    }
    if (lane < 8) ((float2*)agg1)[n * 8 + lane] = f;   // channels 2*lane,2*lane+1
}

__global__ void k_ov1(const int* __restrict__ ovcnt, const int* __restrict__ ov,
                      const float* __restrict__ x, float* __restrict__ agg1) {
    int c = *ovcnt; if (c > OVCAP) c = OVCAP;
    for (int i = blockIdx.x * blockDim.x + threadIdx.x; i < c;
         i += gridDim.x * blockDim.x) {
        int d = ov[2 * i], s = ov[2 * i + 1];
        for (int ch = 0; ch < IN_CH; ch++)
            atomicAdd(&agg1[d * 16 + ch], x[s * IN_CH + ch]);
    }
}

// ---------------- layer 1 dense: h1 = relu(Wl1*mean + Wr1*x + b) -> fp16 ------
__global__ void k_dense1(const float* __restrict__ x, const float* __restrict__ agg1,
                         const int* __restrict__ cnt, const float* __restrict__ Wl,
                         const float* __restrict__ bl, const float* __restrict__ Wr,
                         unsigned* __restrict__ h1h, int N) {
    int lane = threadIdx.x & 63;
    int n = blockIdx.x * 4 + (threadIdx.x >> 6);
    if (n > N) return;
    if (n == N) {
        if (lane < 32) h1h[n * 32 + lane] = 0u;
        return;
    }
    int deg = cnt[n];
    float inv = deg > 0 ? 1.f / (float)deg : 0.f;
    float mv = (lane < 16) ? agg1[n * 16 + lane] * inv : 0.f;
    float xv = (lane < IN_CH) ? x[n * IN_CH + lane] : 0.f;
    float h = bl[lane];
    #pragma unroll
    for (int c = 0; c < IN_CH; c++)
        h += Wl[lane * IN_CH + c] * __shfl(mv, c) + Wr[lane * IN_CH + c] * __shfl(xv, c);
    h = fmaxf(h, 0.f);
    unsigned my = (unsigned)__half_as_ushort(__float2half_rn(h));
    unsigned nx = __shfl_down(my, 1);
    if ((lane & 1) == 0) h1h[n * 32 + (lane >> 1)] = my | (nx << 16);
}

// ------- layer 2 aggregate: packed-fp16 accumulate, fp32 cross-lane reduce ----
__global__ void k_agg2(const uint4* __restrict__ h1h4, const int* __restrict__ col64,
                       float* __restrict__ agg2, int N) {
    int lane = threadIdx.x & 63;
    int n = blockIdx.x * 4 + (threadIdx.x >> 6);
    if (n >= N) return;
    int c8 = lane & 7, sub = lane >> 3;
    const int* cb = col64 + n * PAD;
    int s[8];
    #pragma unroll
    for (int jj = 0; jj < 8; jj++) s[jj] = cb[sub + 8 * jj];
    uint4 v[8];
    #pragma unroll
    for (int jj = 0; jj < 8; jj++) v[jj] = h1h4[s[jj] * 8 + c8];
    __half2 a2[4];
    #pragma unroll
    for (int t = 0; t < 4; t++) a2[t] = __floats2half2_rn(0.f, 0.f);
    #pragma unroll
    for (int jj = 0; jj < 8; jj++) {
        a2[0] = __hadd2(a2[0], *(__half2*)&v[jj].x);
        a2[1] = __hadd2(a2[1], *(__half2*)&v[jj].y);
        a2[2] = __hadd2(a2[2], *(__half2*)&v[jj].z);
        a2[3] = __hadd2(a2[3], *(__half2*)&v[jj].w);
    }
    float acc[8];
    #pragma unroll
    for (int t = 0; t < 4; t++) {
        float2 f = __half22float2(a2[t]);
        acc[2 * t] = f.x; acc[2 * t + 1] = f.y;
    }
    #pragma unroll
    for (int off = 8; off <= 32; off <<= 1) {
        #pragma unroll
        for (int t = 0; t < 8; t++) acc[t] += __shfl_xor(acc[t], off);
    }
    float val = acc[0];                        // channel = 8*c8 + sub
    #pragma unroll
    for (int t = 1; t < 8; t++) if (sub == t) val = acc[t];
    agg2[n * 64 + 8 * c8 + sub] = val;
}

__global__ void k_ov2(const int* __restrict__ ovcnt, const int* __restrict__ ov,
                      const unsigned* __restrict__ h1h, float* __restrict__ agg2) {
    int c = *ovcnt; if (c > OVCAP) c = OVCAP;
    const __half* h1 = (const __half*)h1h;
    for (int i = blockIdx.x * blockDim.x + threadIdx.x; i < c;
         i += gridDim.x * blockDim.x) {
        int d = ov[2 * i], s = ov[2 * i + 1];
        for (int ch = 0; ch < HID; ch++)
            atomicAdd(&agg2[d * 64 + ch], __half2float(h1[s * 64 + ch]));
    }
}

// ---- layer 2 dense as MFMA GEMM; mean division folded into A-fragment build
__global__ __launch_bounds__(256) void k_dense2(
    const float4* __restrict__ agg2_4, const int* __restrict__ cnt,
    const uint4* __restrict__ h1h_u4,
    const __half* __restrict__ wl2h, const __half* __restrict__ wr2h,
    const float* __restrict__ bl, const float* __restrict__ Wlin,
    const float* __restrict__ blin, float* __restrict__ out, int N) {
    union U { uint4 u; half8_t h; };
    int lane = threadIdx.x & 63;
    int wave = blockIdx.x * 4 + (threadIdx.x >> 6);
    int nwaves = gridDim.x * 4;
    int r16 = lane & 15, quad = lane >> 4;
    const uint4* wlu = (const uint4*)wl2h;
    const uint4* wru = (const uint4*)wr2h;
    half8_t bfr[4][4];
    #pragma unroll
    for (int tt = 0; tt < 4; tt++) {
        int o = tt * 16 + r16;
        U t0, t1, t2, t3;
        t0.u = wlu[o * 8 + quad];
        t1.u = wlu[o * 8 + 4 + quad];
        t2.u = wru[o * 8 + quad];
        t3.u = wru[o * 8 + 4 + quad];
        bfr[tt][0] = t0.h; bfr[tt][1] = t1.h; bfr[tt][2] = t2.h; bfr[tt][3] = t3.h;
    }
    float bl_c[4], wl_c[4];
    #pragma unroll
    for (int tt = 0; tt < 4; tt++) {
        bl_c[tt] = bl[tt * 16 + r16];
        wl_c[tt] = Wlin[tt * 16 + r16];
    }
    float b0 = blin[0];
    int ntiles = (N + 15) >> 4;
    for (int t = wave; t < ntiles; t += nwaves) {
        int nb = t * 16;
        int n = nb + r16; if (n >= N) n = N - 1;
        int deg = cnt[n];
        float inv = deg > 0 ? 1.f / (float)deg : 0.f;
        float4 m0 = agg2_4[n * 16 + quad * 2];        // mean ch quad*8 .. +3
        float4 m1 = agg2_4[n * 16 + quad * 2 + 1];    // +4 .. +7
        float4 m2 = agg2_4[n * 16 + 8 + quad * 2];    // 32+quad*8 ..
        float4 m3 = agg2_4[n * 16 + 8 + quad * 2 + 1];
        half8_t a0h, a1h;
        a0h[0] = (_Float16)(m0.x * inv); a0h[1] = (_Float16)(m0.y * inv);
        a0h[2] = (_Float16)(m0.z * inv); a0h[3] = (_Float16)(m0.w * inv);
        a0h[4] = (_Float16)(m1.x * inv); a0h[5] = (_Float16)(m1.y * inv);
        a0h[6] = (_Float16)(m1.z * inv); a0h[7] = (_Float16)(m1.w * inv);
        a1h[0] = (_Float16)(m2.x * inv); a1h[1] = (_Float16)(m2.y * inv);
        a1h[2] = (_Float16)(m2.z * inv); a1h[3] = (_Float16)(m2.w * inv);
        a1h[4] = (_Float16)(m3.x * inv); a1h[5] = (_Float16)(m3.y * inv);
        a1h[6] = (_Float16)(m3.z * inv); a1h[7] = (_Float16)(m3.w * inv);
        U a2, a3;
        a2.u = h1h_u4[n * 8 + quad];
        a3.u = h1h_u4[n * 8 + 4 + quad];
        float p0 = 0.f, p1 = 0.f, p2 = 0.f, p3 = 0.f;
        #pragma unroll
        for (int tt = 0; tt < 4; tt++) {
            f32x4_t c = {0.f, 0.f, 0.f, 0.f};
            c = __builtin_amdgcn_mfma_f32_16x16x32_f16(a0h, bfr[tt][0], c, 0, 0, 0);
            c = __builtin_amdgcn_mfma_f32_16x16x32_f16(a1h, bfr[tt][1], c, 0, 0, 0);
            c = __builtin_amdgcn_mfma_f32_16x16x32_f16(a2.h, bfr[tt][2], c, 0, 0, 0);
            c = __builtin_amdgcn_mfma_f32_16x16x32_f16(a3.h, bfr[tt][3], c, 0, 0, 0);
            p0 += fmaxf(c[0] + bl_c[tt], 0.f) * wl_c[tt];
            p1 += fmaxf(c[1] + bl_c[tt], 0.f) * wl_c[tt];
            p2 += fmaxf(c[2] + bl_c[tt], 0.f) * wl_c[tt];
            p3 += fmaxf(c[3] + bl_c[tt], 0.f) * wl_c[tt];
        }
        #pragma unroll
        for (int off = 1; off <= 8; off <<= 1) {
            p0 += __shfl_xor(p0, off); p1 += __shfl_xor(p1, off);
            p2 += __shfl_xor(p2, off); p3 += __shfl_xor(p3, off);
        }
        if (r16 == 0) {
            int nn = nb + quad * 4;
            if (nn + 3 < N) {
                ((float4*)out)[nn >> 2] = make_float4(p0 + b0, p1 + b0, p2 + b0, p3 + b0);
            } else {
                if (nn + 0 < N) out[nn + 0] = p0 + b0;
                if (nn + 1 < N) out[nn + 1] = p1 + b0;
                if (nn + 2 < N) out[nn + 2] = p2 + b0;
                if (nn + 3 < N) out[nn + 3] = p3 + b0;
            }
        }
    }
}

// ---------------- launch ----------------

extern "C" void kernel_launch(void* const* d_in, const int* in_sizes, int n_in,
                              void* d_out, int out_size, void* d_ws, size_t ws_size,
                              hipStream_t stream) {
    const float* x    = (const float*)d_in[0];
    const int*   ei   = (const int*)d_in[1];
    const float* Wl1  = (const float*)d_in[2];
    const float* bl1  = (const float*)d_in[3];
    const float* Wr1  = (const float*)d_in[4];
    const float* Wl2  = (const float*)d_in[5];
    const float* bl2  = (const float*)d_in[6];
    const float* Wr2  = (const float*)d_in[7];
    const float* Wlin = (const float*)d_in[8];
    const float* blin = (const float*)d_in[9];
    float* out = (float*)d_out;

    int N = in_sizes[0] / IN_CH;   // 100000
    int E = in_sizes[1] / 2;       // 3200000
    const int* srcp = ei;
    const int* dstp = ei + E;

    // workspace (int offsets; total 16,139,040 ints = 64.56 MB, <= round-8 use):
    //  cnt   @ 0          (N+1; ovcnt = cnt[N])
    //  col64 @ 100,032    (6.4M; live bbuild->agg2)
    //    hist overlays col64 @ 100,032 (782*256; dead before bbuild writes)
    //  xph   @ 6,500,032  ((N+1)*8; prep->agg1)
    //  ebuf  @ 7,300,064  (6.4M; scatter->bbuild)
    //  agg1  @ 7,300,064  (1.6M; agg1->dense1; overlays dead ebuf)
    //  agg2  @ 6,500,032  (6.4M; agg2->dense2; overlays dead xph/agg1/ebuf-head)
    //  h1h   @ 12,900,096 ((N+1)*32; dense1->dense2; after agg2 end, ebuf dead)
    //  ov    @ 16,100,128 (2*OVCAP)
    //  wl2h  @ 16,132,896 / wr2h @ 16,134,944 (2048 each)
    //  btot  @ 16,136,992 (1024), bstart @ 16,138,016 (1024)
    int* ws       = (int*)d_ws;
    int* cnt      = ws;
    int* ovcnt    = ws + N;
    int* col64    = ws + 100032;
    int* hist     = ws + 100032;
    unsigned* xph = (unsigned*)(ws + 6500032);
    int2* ebuf    = (int2*)(ws + 7300064);
    float* agg1   = (float*)(ws + 7300064);
    float* agg2   = (float*)(ws + 6500032);
    unsigned* h1h = (unsigned*)(ws + 12900096);
    int* ov       = ws + 16100128;
    __half* wl2h  = (__half*)(ws + 16132896);
    __half* wr2h  = (__half*)(ws + 16134944);
    int* btot     = ws + 16136992;
    int* bstart   = ws + 16138016;

    int nbkt = (N + 127) >> BSH;          // 782
    int csz  = (E + NBLK - 1) / NBLK;     // 12500

    k_prep   <<<((N + 1) * 8 + 255) / 256, 256, 0, stream>>>(x, Wl2, Wr2, xph,
                                                             wl2h, wr2h, ovcnt, N);
    k_hist   <<<NBLK, 256, 0, stream>>>(dstp, hist, E, csz, nbkt);
    k_scanA  <<<nbkt, 256, 0, stream>>>(hist, btot);
    k_scanB  <<<1, 1024, 0, stream>>>(btot, bstart, nbkt);
    k_scatter<<<NBLK, 256, 0, stream>>>(srcp, dstp, hist, bstart, ebuf, E, csz, nbkt);
    k_bbuild <<<nbkt, 256, 0, stream>>>(ebuf, bstart, btot, cnt, col64,
                                        ovcnt, ov, N);

    k_agg1   <<<(N + 3) / 4, 256, 0, stream>>>(xph, col64, agg1, N);
    k_ov1    <<<8, 256, 0, stream>>>(ovcnt, ov, x, agg1);
    k_dense1 <<<(N + 4) / 4, 256, 0, stream>>>(x, agg1, cnt, Wl1, bl1, Wr1, h1h, N);

    k_agg2   <<<(N + 3) / 4, 256, 0, stream>>>((const uint4*)h1h, col64, agg2, N);
    k_ov2    <<<8, 256, 0, stream>>>(ovcnt, ov, h1h, agg2);

    k_dense2 <<<512, 256, 0, stream>>>((const float4*)agg2, cnt, (const uint4*)h1h,
                                       wl2h, wr2h, bl2, Wlin, blin, out, N);
}